// Round 12
// baseline (163.846 us; speedup 1.0000x reference)
//
#include <hip/hip_runtime.h>
#include <stdint.h>

// R38: eliminate the xb round-trip (non-attn, bit-identical class — 2/2).
//  - gemm_hqT loads x as f32 directly and applies the SAME f2bf sequence
//    in-register -> A-operand bytes identical to R37's xb -> hq/hT
//    bit-identical -> absmax exactly 0.0234375.
//  - prep shrinks 2048 -> 1024 blocks (Wc build only); xb write (2MB) and
//    re-read (2MB) deleted; gemm A-traffic 8->16MB (L2-resident).
//  - attn_split / merge4 byte-identical to R37/R35/R33 (attn binary
//    passed 4x: R29, R33, R35, R37).
// CONDEMNED (deterministic per-binary failures): any attn edit — dbuf
// (R28/R30), grid remap (R31), no-LDS (R32/R34), depth-2 prefetch (R36).
// R37 (passed 161.1us): gemm Wc->LDS (+14). R33=R29: 173.8. R22: 198.8.

typedef short bf16x8 __attribute__((ext_vector_type(8)));
typedef short short4v __attribute__((ext_vector_type(4)));
typedef float f32x4 __attribute__((ext_vector_type(4)));
typedef unsigned u32x4 __attribute__((ext_vector_type(4)));

#define LOG2E 1.4426950408889634f

__device__ __forceinline__ short f2bf(float f) {  // RNE
  union { float f; unsigned u; } x;
  x.f = f;
  unsigned r = (x.u + 0x7FFFu + ((x.u >> 16) & 1u)) >> 16;
  return (short)r;
}

__device__ __forceinline__ float rexp2(float x) {  // raw v_exp_f32, no fixup
#if __has_builtin(__builtin_amdgcn_exp2f)
  return __builtin_amdgcn_exp2f(x);
#else
  float r;
  asm("v_exp_f32 %0, %1" : "=v"(r) : "v"(x));
  return r;
#endif
}

__device__ __forceinline__ unsigned cvtpk(float lo, float hi) {
  // D[15:0] = bf16(lo), D[31:16] = bf16(hi), RNE
  unsigned r;
  asm("v_cvt_pk_bf16_f32 %0, %1, %2" : "=v"(r) : "v"(lo), "v"(hi));
  return r;
}

// ---------------- k0: prep = Wc build only (x conversion moved into gemm)
__global__ __launch_bounds__(256) void prep(const float* __restrict__ W,
                                            const float* __restrict__ A,
                                            short* __restrict__ Wc) {
  const int r = blockIdx.x;  // 0..1023
  const int k = threadIdx.x;
  if (r < 512) {
    Wc[r * 256 + k] = f2bf(W[r * 256 + k]);
  } else {
    const int rr = r - 512;
    const int head = rr >> 6, e = rr & 63;
    float acc = 0.f;
    for (int dd = 0; dd < 64; ++dd) {
      acc += A[(head * 64 + dd) * 64 + e] * W[(head * 64 + dd) * 256 + k];
    }
    Wc[r * 256 + k] = f2bf(acc * LOG2E);  // exp2 domain
  }
}

// ---------------- k1: hq = x @ Wc^T (128x128 tile, 8 waves, Wc in LDS,
// x loaded f32 + in-register f2bf). Operand bytes identical to R37.
__global__ __launch_bounds__(512) void gemm_hqT(const float* __restrict__ xf,
                                                const short* __restrict__ Wc,
                                                short* __restrict__ hq,
                                                short* __restrict__ hT) {
  __shared__ short T[128 * 132];    // 33.8KB, used when blockIdx.x < 4
  __shared__ short WcS[128 * 264];  // 67.6KB: 256 cols padded to 264
  const int tid = threadIdx.x;
  const int wave = tid >> 6, lane = tid & 63;
  const int quad = lane >> 4, c = lane & 15;
  const int row0w = blockIdx.y * 128 + wave * 16;  // this wave's 16 rows
  const int col0 = blockIdx.x * 128;
  const bool doT = (blockIdx.x < 4);  // block-uniform

  // stage Wc rows col0..col0+127 (64KB) into LDS, 16B/lane coalesced.
  {
    const short* src = Wc + col0 * 256;
#pragma unroll
    for (int j = 0; j < 8; ++j) {
      const int idx = tid + j * 512;        // 0..4095 chunks of 8 shorts
      const int r = idx >> 5, col8 = idx & 31;
      bf16x8 v = *(const bf16x8*)(src + idx * 8);
      *(bf16x8*)&WcS[r * 264 + col8 * 8] = v;
    }
  }
  __syncthreads();

  f32x4 acc[8];
#pragma unroll
  for (int nt = 0; nt < 8; ++nt) acc[nt] = (f32x4){0.f, 0.f, 0.f, 0.f};
#pragma unroll
  for (int ks = 0; ks < 8; ++ks) {
    const float* ap = xf + (row0w + c) * 256 + ks * 32 + quad * 8;
    float4 af0 = *(const float4*)ap;
    float4 af1 = *(const float4*)(ap + 4);
    bf16x8 a = {f2bf(af0.x), f2bf(af0.y), f2bf(af0.z), f2bf(af0.w),
                f2bf(af1.x), f2bf(af1.y), f2bf(af1.z), f2bf(af1.w)};
#pragma unroll
    for (int nt = 0; nt < 8; ++nt) {
      bf16x8 b = *(const bf16x8*)&WcS[(nt * 16 + c) * 264 + ks * 32 + quad * 8];
      acc[nt] = __builtin_amdgcn_mfma_f32_16x16x32_bf16(a, b, acc[nt], 0, 0, 0);
    }
  }
#pragma unroll
  for (int nt = 0; nt < 8; ++nt)
#pragma unroll
    for (int r = 0; r < 4; ++r) {
      const short v = f2bf(acc[nt][r]);
      hq[(row0w + quad * 4 + r) * 1024 + col0 + nt * 16 + c] = v;
      if (doT) T[(wave * 16 + quad * 4 + r) * 132 + nt * 16 + c] = v;
    }

  if (doT) {  // emit transposed hT[feature][node] for features col0..col0+127
    __syncthreads();
    const int fl = tid >> 2;             // 0..127: local feature
    const int qtr = (tid & 3) * 32;      // node quarter: 0/32/64/96
    short* dst = hT + (size_t)(col0 + fl) * 4096 + blockIdx.y * 128 + qtr;
#pragma unroll
    for (int g = 0; g < 4; ++g) {
      bf16x8 v = {T[(qtr + g * 8 + 0) * 132 + fl], T[(qtr + g * 8 + 1) * 132 + fl],
                  T[(qtr + g * 8 + 2) * 132 + fl], T[(qtr + g * 8 + 3) * 132 + fl],
                  T[(qtr + g * 8 + 4) * 132 + fl], T[(qtr + g * 8 + 5) * 132 + fl],
                  T[(qtr + g * 8 + 6) * 132 + fl], T[(qtr + g * 8 + 7) * 132 + fl]};
      *(bf16x8*)(dst + g * 8) = v;
    }
  }
}

// ---------------- k2: no-max flash, 32 queries/wave, K-split x4.
// [byte-identical R37/R35/R33/R29 — FROZEN]
__global__ __launch_bounds__(256, 4) void attn_split(const short* __restrict__ hq,
                                                     const short* __restrict__ hT,
                                                     short* __restrict__ po,
                                                     float* __restrict__ pl) {
  const int tid = threadIdx.x;
  const int wave = tid >> 6, lane = tid & 63;
  const int quad = lane >> 4, c = lane & 15;
  const int head = blockIdx.y;
  const int q0 = blockIdx.x * 128 + wave * 32;

  __shared__ __align__(16) short K_lds[64 * 68];   // [perm-row][dim]
  __shared__ __align__(16) short Vt_lds[64 * 68];  // [dim][node] identity

  bf16x8 qf[2][2];
#pragma unroll
  for (int p = 0; p < 2; ++p) {
    const short* qb = hq + (q0 + p * 16 + c) * 1024 + 512 + head * 64 + quad * 8;
    qf[p][0] = *(const bf16x8*)qb;
    qf[p][1] = *(const bf16x8*)(qb + 32);
  }
  const short one = (short)0x3F80;
  const bf16x8 ones = {one, one, one, one, one, one, one, one};

  f32x4 o[2][4], ol[2];
#pragma unroll
  for (int p = 0; p < 2; ++p) {
#pragma unroll
    for (int mt = 0; mt < 4; ++mt) o[p][mt] = (f32x4){0.f, 0.f, 0.f, 0.f};
    ol[p] = (f32x4){0.f, 0.f, 0.f, 0.f};
  }

  const int kt0 = blockIdx.z * 16;

  // async staging: per-thread tile chunks, loaded one iteration ahead.
  const int key0 = tid >> 3, dc0 = tid & 7;        // key0 in 0..31
  const int key1 = key0 + 32, dc1 = dc0;           // key1 in 32..63
  // kappa(key): K_lds row for node 'key' (R29-verified).
  const int kperm0 = (((key0 >> 2) & 1) << 4) | (((key0 >> 4) & 1) << 3) |
                     (((key0 >> 3) & 1) << 2) | (key0 & 3);
  const int kperm1 = kperm0 + 32;
  const short* kp0 = hq + (size_t)(kt0 * 64 + key0) * 1024 + head * 64 + dc0 * 8;
  const short* kp1 = hq + (size_t)(kt0 * 64 + key1) * 1024 + head * 64 + dc1 * 8;
  const short* vp0 = hT + (size_t)(head * 64 + key0) * 4096 + kt0 * 64 + dc0 * 8;
  const short* vp1 = hT + (size_t)(head * 64 + key1) * 4096 + kt0 * 64 + dc1 * 8;
  bf16x8 kr0 = *(const bf16x8*)kp0;
  bf16x8 kr1 = *(const bf16x8*)kp1;
  bf16x8 vr0 = *(const bf16x8*)vp0;
  bf16x8 vr1 = *(const bf16x8*)vp1;

  for (int kt = kt0; kt < kt0 + 16; ++kt) {
    __syncthreads();  // previous tile fully consumed
    *(bf16x8*)&K_lds[kperm0 * 68 + dc0 * 8] = kr0;
    *(bf16x8*)&K_lds[kperm1 * 68 + dc1 * 8] = kr1;
    *(bf16x8*)&Vt_lds[key0 * 68 + dc0 * 8] = vr0;
    *(bf16x8*)&Vt_lds[key1 * 68 + dc1 * 8] = vr1;
    // issue next tile's loads; latency hides under this tile's compute.
    const int adv = (kt + 1 < kt0 + 16) ? 1 : 0;
    kp0 += adv * 65536; kp1 += adv * 65536;
    vp0 += adv * 64;    vp1 += adv * 64;
    kr0 = *(const bf16x8*)kp0;
    kr1 = *(const bf16x8*)kp1;
    vr0 = *(const bf16x8*)vp0;
    vr1 = *(const bf16x8*)vp1;
    __syncthreads();  // staging visible

    // scores vs permuted K rows -> P stays in registers (pw)
    unsigned pw[2][8];
#pragma unroll
    for (int mt = 0; mt < 4; ++mt) {
      bf16x8 a0 = *(const bf16x8*)&K_lds[(mt * 16 + c) * 68 + quad * 8];
      bf16x8 a1 = *(const bf16x8*)&K_lds[(mt * 16 + c) * 68 + 32 + quad * 8];
#pragma unroll
      for (int p = 0; p < 2; ++p) {
        f32x4 s = (f32x4){0.f, 0.f, 0.f, 0.f};
        s = __builtin_amdgcn_mfma_f32_16x16x32_bf16(a0, qf[p][0], s, 0, 0, 0);
        s = __builtin_amdgcn_mfma_f32_16x16x32_bf16(a1, qf[p][1], s, 0, 0, 0);
        const float p0 = rexp2(fmaxf(s[0], 0.2f * s[0]));
        const float p1 = rexp2(fmaxf(s[1], 0.2f * s[1]));
        const float p2 = rexp2(fmaxf(s[2], 0.2f * s[2]));
        const float p3 = rexp2(fmaxf(s[3], 0.2f * s[3]));
        pw[p][mt * 2] = cvtpk(p0, p1);
        pw[p][mt * 2 + 1] = cvtpk(p2, p3);
      }
    }
    // P fragments directly from regs (pairing with identity Vt, R29-verified)
    bf16x8 pb[2][2];
#pragma unroll
    for (int p = 0; p < 2; ++p) {
      u32x4 lo4 = {pw[p][0], pw[p][1], pw[p][2], pw[p][3]};
      u32x4 hi4 = {pw[p][4], pw[p][5], pw[p][6], pw[p][7]};
      pb[p][0] = __builtin_bit_cast(bf16x8, lo4);
      pb[p][1] = __builtin_bit_cast(bf16x8, hi4);
    }
    // PV: Vt frags shared across both panels
#pragma unroll
    for (int mt = 0; mt < 4; ++mt) {
      bf16x8 va0 = *(const bf16x8*)&Vt_lds[(mt * 16 + c) * 68 + quad * 8];
      bf16x8 va1 = *(const bf16x8*)&Vt_lds[(mt * 16 + c) * 68 + 32 + quad * 8];
#pragma unroll
      for (int p = 0; p < 2; ++p) {
        o[p][mt] = __builtin_amdgcn_mfma_f32_16x16x32_bf16(va0, pb[p][0], o[p][mt], 0, 0, 0);
        o[p][mt] = __builtin_amdgcn_mfma_f32_16x16x32_bf16(va1, pb[p][1], o[p][mt], 0, 0, 0);
      }
    }
#pragma unroll
    for (int p = 0; p < 2; ++p) {
      ol[p] = __builtin_amdgcn_mfma_f32_16x16x32_bf16(ones, pb[p][0], ol[p], 0, 0, 0);
      ol[p] = __builtin_amdgcn_mfma_f32_16x16x32_bf16(ones, pb[p][1], ol[p], 0, 0, 0);
    }
  }

  // epilogue: bf16 partials + l per panel (pbi matches merge4 layout)
  const int pbi = (blockIdx.x * 8 + blockIdx.y) * 4 + blockIdx.z;
  short* po_b = po + (size_t)pbi * 8192;  // [128 q][64 d]
#pragma unroll
  for (int p = 0; p < 2; ++p) {
    const int ql = wave * 32 + p * 16 + c;
#pragma unroll
    for (int mt = 0; mt < 4; ++mt) {
      short4v o4 = {f2bf(o[p][mt][0]), f2bf(o[p][mt][1]),
                    f2bf(o[p][mt][2]), f2bf(o[p][mt][3])};
      *(short4v*)&po_b[ql * 64 + mt * 16 + quad * 4] = o4;
    }
    if (quad == 0) pl[pbi * 128 + ql] = ol[p][0];
  }
}

// ---------------- k3: merge 4 kslices (bf16 partials -> f32 out)
// [byte-identical R37]
__global__ __launch_bounds__(256) void merge4(const short* __restrict__ po,
                                              const float* __restrict__ pl,
                                              float* __restrict__ out) {
  const int qt = blockIdx.x, head = blockIdx.y, t = threadIdx.x;  // qt: 64-q group
  const int q = t >> 2, dg = t & 3;
  const int q128 = (qt & 1) * 64 + q;
  const int pbb = ((qt >> 1) * 8 + head) * 4;
  const float inv = 1.0f / (pl[pbb * 128 + q128] + pl[(pbb + 1) * 128 + q128] +
                            pl[(pbb + 2) * 128 + q128] + pl[(pbb + 3) * 128 + q128]);
  float a[16];
#pragma unroll
  for (int i = 0; i < 16; ++i) a[i] = 0.f;
#pragma unroll
  for (int z = 0; z < 4; ++z) {
    const short* p = po + (size_t)(pbb + z) * 8192 + q128 * 64 + dg * 16;
    bf16x8 lo = *(const bf16x8*)p;
    bf16x8 hi = *(const bf16x8*)(p + 8);
#pragma unroll
    for (int i = 0; i < 8; ++i) {
      union { unsigned u; float f; } x, y;
      x.u = ((unsigned)(unsigned short)lo[i]) << 16;
      y.u = ((unsigned)(unsigned short)hi[i]) << 16;
      a[i] += x.f;
      a[i + 8] += y.f;
    }
  }
  float* op = out + (qt * 64 + q) * 512 + head * 64 + dg * 16;
#pragma unroll
  for (int i = 0; i < 4; ++i) {
    float4 r = {a[i * 4] * inv, a[i * 4 + 1] * inv, a[i * 4 + 2] * inv, a[i * 4 + 3] * inv};
    *(float4*)(op + i * 4) = r;
  }
}

extern "C" void kernel_launch(void* const* d_in, const int* in_sizes, int n_in,
                              void* d_out, int out_size, void* d_ws, size_t ws_size,
                              hipStream_t stream) {
  const float* x = (const float*)d_in[0];
  const float* W = (const float*)d_in[2];
  const float* A = (const float*)d_in[3];
  for (int i = 0; i < n_in; ++i) {
    if (in_sizes[i] == 4096 * 256) x = (const float*)d_in[i];
    else if (in_sizes[i] == 512 * 256) W = (const float*)d_in[i];
    else if (in_sizes[i] == 8 * 64 * 64) A = (const float*)d_in[i];
  }

  float* out = (float*)d_out;                 // [4096][512] f32
  short* xb = (short*)d_ws;                   // (unused slot kept for layout)
  short* Wc = xb + 4096 * 256;                // 0.5 MB
  short* hq = Wc + 1024 * 256;                // 8 MB
  short* hT = hq + 4096 * 1024;               // 4 MB
  short* po = hT + 512 * 4096;                // 1024*8192*2 = 16.8 MB
  float* pl = (float*)(po + (size_t)1024 * 8192);  // 0.5 MB

  prep<<<dim3(1024), dim3(256), 0, stream>>>(W, A, Wc);
  gemm_hqT<<<dim3(8, 32), dim3(512), 0, stream>>>(x, Wc, hq, hT);
  attn_split<<<dim3(32, 8, 4), dim3(256), 0, stream>>>(hq, hT, po, pl);
  merge4<<<dim3(64, 8), dim3(256), 0, stream>>>(po, pl, out);
}

// Round 13
// 161.095 us; speedup vs baseline: 1.0171x; 1.0171x over previous
//
#include <hip/hip_runtime.h>
#include <stdint.h>

// R39 = R37 byte-exact (session best, 161.1us): terminal submission.
// R38's xb-fold was -2.7us (gemm f32 A-traffic + in-loop cvt outweighed the
// deleted prep pass). All remaining levers exhausted:
//  - attn edits: FROZEN (2 pass / 6 deterministic per-binary fails, incl.
//    three operand-identity-proven variants R31/R32/R36).
//  - non-attn bit-identical class: mined (R37's Wc->LDS +14us was the win;
//    R35/R38 traffic reshuffles neutral).
// Session: 198.8 -> 161.1us (-19%). attn 82->53 (rexp2, cvt_pk, async-stage,
// reg-P via kappa-permuted K rows); gemm +14 (Wc LDS staging).
// attn binary passed 5x: R29, R33, R35, R37, R38.

typedef short bf16x8 __attribute__((ext_vector_type(8)));
typedef short short4v __attribute__((ext_vector_type(4)));
typedef float f32x4 __attribute__((ext_vector_type(4)));
typedef unsigned u32x4 __attribute__((ext_vector_type(4)));

#define LOG2E 1.4426950408889634f

__device__ __forceinline__ short f2bf(float f) {  // RNE
  union { float f; unsigned u; } x;
  x.f = f;
  unsigned r = (x.u + 0x7FFFu + ((x.u >> 16) & 1u)) >> 16;
  return (short)r;
}

__device__ __forceinline__ float rexp2(float x) {  // raw v_exp_f32, no fixup
#if __has_builtin(__builtin_amdgcn_exp2f)
  return __builtin_amdgcn_exp2f(x);
#else
  float r;
  asm("v_exp_f32 %0, %1" : "=v"(r) : "v"(x));
  return r;
#endif
}

__device__ __forceinline__ unsigned cvtpk(float lo, float hi) {
  // D[15:0] = bf16(lo), D[31:16] = bf16(hi), RNE
  unsigned r;
  asm("v_cvt_pk_bf16_f32 %0, %1, %2" : "=v"(r) : "v"(lo), "v"(hi));
  return r;
}

// ---------------- k0: fused prep (x cvt + Wc build)
__global__ __launch_bounds__(256) void prep(const float* __restrict__ xf,
                                            const float* __restrict__ W,
                                            const float* __restrict__ A,
                                            short* __restrict__ xb,
                                            short* __restrict__ Wc) {
  const int b = blockIdx.x;
  if (b < 1024) {
    const int i = (b * 256 + threadIdx.x) * 4;
    float4 v = *(const float4*)(xf + i);
    short4v s = {f2bf(v.x), f2bf(v.y), f2bf(v.z), f2bf(v.w)};
    *(short4v*)(xb + i) = s;
  } else {
    const int r = b - 1024;
    const int k = threadIdx.x;
    if (r < 512) {
      Wc[r * 256 + k] = f2bf(W[r * 256 + k]);
    } else {
      const int rr = r - 512;
      const int head = rr >> 6, e = rr & 63;
      float acc = 0.f;
      for (int dd = 0; dd < 64; ++dd) {
        acc += A[(head * 64 + dd) * 64 + e] * W[(head * 64 + dd) * 256 + k];
      }
      Wc[r * 256 + k] = f2bf(acc * LOG2E);  // exp2 domain
    }
  }
}

// ---------------- k1: hq = x @ Wc^T (128x128 tile, 8 waves, Wc in LDS).
__global__ __launch_bounds__(512) void gemm_hqT(const short* __restrict__ x,
                                                const short* __restrict__ Wc,
                                                short* __restrict__ hq,
                                                short* __restrict__ hT) {
  __shared__ short T[128 * 132];    // 33.8KB, used when blockIdx.x < 4
  __shared__ short WcS[128 * 264];  // 67.6KB: 256 cols padded to 264
  const int tid = threadIdx.x;
  const int wave = tid >> 6, lane = tid & 63;
  const int quad = lane >> 4, c = lane & 15;
  const int row0w = blockIdx.y * 128 + wave * 16;  // this wave's 16 rows
  const int col0 = blockIdx.x * 128;
  const bool doT = (blockIdx.x < 4);  // block-uniform

  // stage Wc rows col0..col0+127 (64KB) into LDS, 16B/lane coalesced.
  {
    const short* src = Wc + col0 * 256;
#pragma unroll
    for (int j = 0; j < 8; ++j) {
      const int idx = tid + j * 512;        // 0..4095 chunks of 8 shorts
      const int r = idx >> 5, col8 = idx & 31;
      bf16x8 v = *(const bf16x8*)(src + idx * 8);
      *(bf16x8*)&WcS[r * 264 + col8 * 8] = v;
    }
  }
  __syncthreads();

  f32x4 acc[8];
#pragma unroll
  for (int nt = 0; nt < 8; ++nt) acc[nt] = (f32x4){0.f, 0.f, 0.f, 0.f};
#pragma unroll
  for (int ks = 0; ks < 8; ++ks) {
    bf16x8 a = *(const bf16x8*)(x + (row0w + c) * 256 + ks * 32 + quad * 8);
#pragma unroll
    for (int nt = 0; nt < 8; ++nt) {
      bf16x8 b = *(const bf16x8*)&WcS[(nt * 16 + c) * 264 + ks * 32 + quad * 8];
      acc[nt] = __builtin_amdgcn_mfma_f32_16x16x32_bf16(a, b, acc[nt], 0, 0, 0);
    }
  }
#pragma unroll
  for (int nt = 0; nt < 8; ++nt)
#pragma unroll
    for (int r = 0; r < 4; ++r) {
      const short v = f2bf(acc[nt][r]);
      hq[(row0w + quad * 4 + r) * 1024 + col0 + nt * 16 + c] = v;
      if (doT) T[(wave * 16 + quad * 4 + r) * 132 + nt * 16 + c] = v;
    }

  if (doT) {  // emit transposed hT[feature][node] for features col0..col0+127
    __syncthreads();
    const int fl = tid >> 2;             // 0..127: local feature
    const int qtr = (tid & 3) * 32;      // node quarter: 0/32/64/96
    short* dst = hT + (size_t)(col0 + fl) * 4096 + blockIdx.y * 128 + qtr;
#pragma unroll
    for (int g = 0; g < 4; ++g) {
      bf16x8 v = {T[(qtr + g * 8 + 0) * 132 + fl], T[(qtr + g * 8 + 1) * 132 + fl],
                  T[(qtr + g * 8 + 2) * 132 + fl], T[(qtr + g * 8 + 3) * 132 + fl],
                  T[(qtr + g * 8 + 4) * 132 + fl], T[(qtr + g * 8 + 5) * 132 + fl],
                  T[(qtr + g * 8 + 6) * 132 + fl], T[(qtr + g * 8 + 7) * 132 + fl]};
      *(bf16x8*)(dst + g * 8) = v;
    }
  }
}

// ---------------- k2: no-max flash, 32 queries/wave, K-split x4.
// [FROZEN — passed 5x]
__global__ __launch_bounds__(256, 4) void attn_split(const short* __restrict__ hq,
                                                     const short* __restrict__ hT,
                                                     short* __restrict__ po,
                                                     float* __restrict__ pl) {
  const int tid = threadIdx.x;
  const int wave = tid >> 6, lane = tid & 63;
  const int quad = lane >> 4, c = lane & 15;
  const int head = blockIdx.y;
  const int q0 = blockIdx.x * 128 + wave * 32;

  __shared__ __align__(16) short K_lds[64 * 68];   // [perm-row][dim]
  __shared__ __align__(16) short Vt_lds[64 * 68];  // [dim][node] identity

  bf16x8 qf[2][2];
#pragma unroll
  for (int p = 0; p < 2; ++p) {
    const short* qb = hq + (q0 + p * 16 + c) * 1024 + 512 + head * 64 + quad * 8;
    qf[p][0] = *(const bf16x8*)qb;
    qf[p][1] = *(const bf16x8*)(qb + 32);
  }
  const short one = (short)0x3F80;
  const bf16x8 ones = {one, one, one, one, one, one, one, one};

  f32x4 o[2][4], ol[2];
#pragma unroll
  for (int p = 0; p < 2; ++p) {
#pragma unroll
    for (int mt = 0; mt < 4; ++mt) o[p][mt] = (f32x4){0.f, 0.f, 0.f, 0.f};
    ol[p] = (f32x4){0.f, 0.f, 0.f, 0.f};
  }

  const int kt0 = blockIdx.z * 16;

  // async staging: per-thread tile chunks, loaded one iteration ahead.
  const int key0 = tid >> 3, dc0 = tid & 7;        // key0 in 0..31
  const int key1 = key0 + 32, dc1 = dc0;           // key1 in 32..63
  // kappa(key): K_lds row for node 'key' (R29-verified).
  const int kperm0 = (((key0 >> 2) & 1) << 4) | (((key0 >> 4) & 1) << 3) |
                     (((key0 >> 3) & 1) << 2) | (key0 & 3);
  const int kperm1 = kperm0 + 32;
  const short* kp0 = hq + (size_t)(kt0 * 64 + key0) * 1024 + head * 64 + dc0 * 8;
  const short* kp1 = hq + (size_t)(kt0 * 64 + key1) * 1024 + head * 64 + dc1 * 8;
  const short* vp0 = hT + (size_t)(head * 64 + key0) * 4096 + kt0 * 64 + dc0 * 8;
  const short* vp1 = hT + (size_t)(head * 64 + key1) * 4096 + kt0 * 64 + dc1 * 8;
  bf16x8 kr0 = *(const bf16x8*)kp0;
  bf16x8 kr1 = *(const bf16x8*)kp1;
  bf16x8 vr0 = *(const bf16x8*)vp0;
  bf16x8 vr1 = *(const bf16x8*)vp1;

  for (int kt = kt0; kt < kt0 + 16; ++kt) {
    __syncthreads();  // previous tile fully consumed
    *(bf16x8*)&K_lds[kperm0 * 68 + dc0 * 8] = kr0;
    *(bf16x8*)&K_lds[kperm1 * 68 + dc1 * 8] = kr1;
    *(bf16x8*)&Vt_lds[key0 * 68 + dc0 * 8] = vr0;
    *(bf16x8*)&Vt_lds[key1 * 68 + dc1 * 8] = vr1;
    // issue next tile's loads; latency hides under this tile's compute.
    const int adv = (kt + 1 < kt0 + 16) ? 1 : 0;
    kp0 += adv * 65536; kp1 += adv * 65536;
    vp0 += adv * 64;    vp1 += adv * 64;
    kr0 = *(const bf16x8*)kp0;
    kr1 = *(const bf16x8*)kp1;
    vr0 = *(const bf16x8*)vp0;
    vr1 = *(const bf16x8*)vp1;
    __syncthreads();  // staging visible

    // scores vs permuted K rows -> P stays in registers (pw)
    unsigned pw[2][8];
#pragma unroll
    for (int mt = 0; mt < 4; ++mt) {
      bf16x8 a0 = *(const bf16x8*)&K_lds[(mt * 16 + c) * 68 + quad * 8];
      bf16x8 a1 = *(const bf16x8*)&K_lds[(mt * 16 + c) * 68 + 32 + quad * 8];
#pragma unroll
      for (int p = 0; p < 2; ++p) {
        f32x4 s = (f32x4){0.f, 0.f, 0.f, 0.f};
        s = __builtin_amdgcn_mfma_f32_16x16x32_bf16(a0, qf[p][0], s, 0, 0, 0);
        s = __builtin_amdgcn_mfma_f32_16x16x32_bf16(a1, qf[p][1], s, 0, 0, 0);
        const float p0 = rexp2(fmaxf(s[0], 0.2f * s[0]));
        const float p1 = rexp2(fmaxf(s[1], 0.2f * s[1]));
        const float p2 = rexp2(fmaxf(s[2], 0.2f * s[2]));
        const float p3 = rexp2(fmaxf(s[3], 0.2f * s[3]));
        pw[p][mt * 2] = cvtpk(p0, p1);
        pw[p][mt * 2 + 1] = cvtpk(p2, p3);
      }
    }
    // P fragments directly from regs (pairing with identity Vt, R29-verified)
    bf16x8 pb[2][2];
#pragma unroll
    for (int p = 0; p < 2; ++p) {
      u32x4 lo4 = {pw[p][0], pw[p][1], pw[p][2], pw[p][3]};
      u32x4 hi4 = {pw[p][4], pw[p][5], pw[p][6], pw[p][7]};
      pb[p][0] = __builtin_bit_cast(bf16x8, lo4);
      pb[p][1] = __builtin_bit_cast(bf16x8, hi4);
    }
    // PV: Vt frags shared across both panels
#pragma unroll
    for (int mt = 0; mt < 4; ++mt) {
      bf16x8 va0 = *(const bf16x8*)&Vt_lds[(mt * 16 + c) * 68 + quad * 8];
      bf16x8 va1 = *(const bf16x8*)&Vt_lds[(mt * 16 + c) * 68 + 32 + quad * 8];
#pragma unroll
      for (int p = 0; p < 2; ++p) {
        o[p][mt] = __builtin_amdgcn_mfma_f32_16x16x32_bf16(va0, pb[p][0], o[p][mt], 0, 0, 0);
        o[p][mt] = __builtin_amdgcn_mfma_f32_16x16x32_bf16(va1, pb[p][1], o[p][mt], 0, 0, 0);
      }
    }
#pragma unroll
    for (int p = 0; p < 2; ++p) {
      ol[p] = __builtin_amdgcn_mfma_f32_16x16x32_bf16(ones, pb[p][0], ol[p], 0, 0, 0);
      ol[p] = __builtin_amdgcn_mfma_f32_16x16x32_bf16(ones, pb[p][1], ol[p], 0, 0, 0);
    }
  }

  // epilogue: bf16 partials + l per panel (pbi matches merge4 layout)
  const int pbi = (blockIdx.x * 8 + blockIdx.y) * 4 + blockIdx.z;
  short* po_b = po + (size_t)pbi * 8192;  // [128 q][64 d]
#pragma unroll
  for (int p = 0; p < 2; ++p) {
    const int ql = wave * 32 + p * 16 + c;
#pragma unroll
    for (int mt = 0; mt < 4; ++mt) {
      short4v o4 = {f2bf(o[p][mt][0]), f2bf(o[p][mt][1]),
                    f2bf(o[p][mt][2]), f2bf(o[p][mt][3])};
      *(short4v*)&po_b[ql * 64 + mt * 16 + quad * 4] = o4;
    }
    if (quad == 0) pl[pbi * 128 + ql] = ol[p][0];
  }
}

// ---------------- k3: merge 4 kslices (bf16 partials -> f32 out)
__global__ __launch_bounds__(256) void merge4(const short* __restrict__ po,
                                              const float* __restrict__ pl,
                                              float* __restrict__ out) {
  const int qt = blockIdx.x, head = blockIdx.y, t = threadIdx.x;  // qt: 64-q group
  const int q = t >> 2, dg = t & 3;
  const int q128 = (qt & 1) * 64 + q;
  const int pbb = ((qt >> 1) * 8 + head) * 4;
  const float inv = 1.0f / (pl[pbb * 128 + q128] + pl[(pbb + 1) * 128 + q128] +
                            pl[(pbb + 2) * 128 + q128] + pl[(pbb + 3) * 128 + q128]);
  float a[16];
#pragma unroll
  for (int i = 0; i < 16; ++i) a[i] = 0.f;
#pragma unroll
  for (int z = 0; z < 4; ++z) {
    const short* p = po + (size_t)(pbb + z) * 8192 + q128 * 64 + dg * 16;
    bf16x8 lo = *(const bf16x8*)p;
    bf16x8 hi = *(const bf16x8*)(p + 8);
#pragma unroll
    for (int i = 0; i < 8; ++i) {
      union { unsigned u; float f; } x, y;
      x.u = ((unsigned)(unsigned short)lo[i]) << 16;
      y.u = ((unsigned)(unsigned short)hi[i]) << 16;
      a[i] += x.f;
      a[i + 8] += y.f;
    }
  }
  float* op = out + (qt * 64 + q) * 512 + head * 64 + dg * 16;
#pragma unroll
  for (int i = 0; i < 4; ++i) {
    float4 r = {a[i * 4] * inv, a[i * 4 + 1] * inv, a[i * 4 + 2] * inv, a[i * 4 + 3] * inv};
    *(float4*)(op + i * 4) = r;
  }
}

extern "C" void kernel_launch(void* const* d_in, const int* in_sizes, int n_in,
                              void* d_out, int out_size, void* d_ws, size_t ws_size,
                              hipStream_t stream) {
  const float* x = (const float*)d_in[0];
  const float* W = (const float*)d_in[2];
  const float* A = (const float*)d_in[3];
  for (int i = 0; i < n_in; ++i) {
    if (in_sizes[i] == 4096 * 256) x = (const float*)d_in[i];
    else if (in_sizes[i] == 512 * 256) W = (const float*)d_in[i];
    else if (in_sizes[i] == 8 * 64 * 64) A = (const float*)d_in[i];
  }

  float* out = (float*)d_out;                 // [4096][512] f32
  short* xb = (short*)d_ws;                   // 2 MB
  short* Wc = xb + 4096 * 256;                // 0.5 MB
  short* hq = Wc + 1024 * 256;                // 8 MB
  short* hT = hq + 4096 * 1024;               // 4 MB
  short* po = hT + 512 * 4096;                // 1024*8192*2 = 16.8 MB
  float* pl = (float*)(po + (size_t)1024 * 8192);  // 0.5 MB

  prep<<<dim3(2048), dim3(256), 0, stream>>>(x, W, A, xb, Wc);
  gemm_hqT<<<dim3(8, 32), dim3(512), 0, stream>>>(xb, Wc, hq, hT);
  attn_split<<<dim3(32, 8, 4), dim3(256), 0, stream>>>(hq, hT, po, pl);
  merge4<<<dim3(64, 8), dim3(256), 0, stream>>>(po, pl, out);
}